// Round 5
// baseline (300.503 us; speedup 1.0000x reference)
//
#include <hip/hip_runtime.h>
#include <hip/hip_bf16.h>
#include <stdint.h>

#define IN_F   4096
#define OUT_F  4096
#define M_ROWS 2048
#define NG     32
#define GRP    128

typedef int   v4i  __attribute__((ext_vector_type(4)));
typedef float f32x4 __attribute__((ext_vector_type(4)));

typedef const void __attribute__((address_space(1))) cv_g;
typedef void       __attribute__((address_space(3))) v_l;

__device__ __forceinline__ void async16(const void* g, void* l) {
  // global -> LDS DMA, 16B/lane; LDS dest = wave-uniform base + lane*16.
  __builtin_amdgcn_global_load_lds((cv_g*)g, (v_l*)l, 16, 0, 0);
}

// perm dtype flag (fallback path only): 1 if int64, 0 if int32.
__device__ int g_perm_is64;

__global__ void decode_flag(const void* __restrict__ perm_raw) {
  if (threadIdx.x == 0 && blockIdx.x == 0) {
    const int* w = (const int*)perm_raw;
    int ok = 1;
    for (int j = 0; j < 32; ++j) {
      int lo = w[2 * j], hi = w[2 * j + 1];
      if (hi != 0 || lo < 0 || lo >= IN_F) { ok = 0; break; }
    }
    g_perm_is64 = ok;
  }
}

// Fused preprocessing (int8 edition) -- unchanged from verified version.
__global__ __launch_bounds__(256) void prep(const float* __restrict__ x,
                                            const int* __restrict__ w_q,
                                            const void* __restrict__ perm_raw,
                                            char* __restrict__ xq,
                                            char* __restrict__ w8,
                                            float* __restrict__ sxr) {
  __shared__ float sx[IN_F];
  __shared__ float red[4];
  __shared__ int sflag;
  const int b = blockIdx.x;
  const int t = threadIdx.x;

  if (b < M_ROWS) {
    const int m = b;
    const float* xr = x + (size_t)m * IN_F;
#pragma unroll
    for (int u = 0; u < 4; ++u) {
      int idx = (u * 256 + t) * 4;
      *(float4*)&sx[idx] = *(const float4*)&xr[idx];
    }
    if (t < 64) {
      const int* w = (const int*)perm_raw;
      int j = t & 31;
      int lo = w[2 * j], hi = w[2 * j + 1];
      int cond = (hi == 0 && lo >= 0 && lo < IN_F);
      unsigned long long bal = __ballot(cond);
      if (t == 0) sflag = (bal == ~0ull) ? 1 : 0;
    }
    __syncthreads();
    const int f = sflag;
    const long long* p64 = (const long long*)perm_raw;
    const int*       p32 = (const int*)perm_raw;
    const int jb = t * 16;
    float vals[16];
    float lmax = 0.f;
#pragma unroll
    for (int u = 0; u < 16; ++u) {
      int pj = f ? (int)p64[jb + u] : p32[jb + u];
      float v = sx[pj];
      vals[u] = v;
      lmax = fmaxf(lmax, fabsf(v));
    }
#pragma unroll
    for (int d = 1; d < 64; d <<= 1)
      lmax = fmaxf(lmax, __shfl_xor(lmax, d, 64));
    if ((t & 63) == 0) red[t >> 6] = lmax;
    __syncthreads();
    float rmax = fmaxf(fmaxf(red[0], red[1]), fmaxf(red[2], red[3]));
    float inv = (rmax > 0.f) ? 127.f / rmax : 0.f;
    if (t == 0) sxr[m] = rmax / 127.f;
    char q[16] __attribute__((aligned(16)));
#pragma unroll
    for (int u = 0; u < 16; ++u)
      q[u] = (char)__float2int_rn(vals[u] * inv);
    *(uint4*)(xq + (size_t)m * IN_F + jb) = *(const uint4*)q;
  } else {
    const int o  = b - M_ROWS;
    const int kb = t * 16;
    const int* wr = w_q + (size_t)o * IN_F + kb;
    int4 w0 = *(const int4*)(wr + 0);
    int4 w1 = *(const int4*)(wr + 4);
    int4 w2 = *(const int4*)(wr + 8);
    int4 w3 = *(const int4*)(wr + 12);
    char q[16] __attribute__((aligned(16)));
    q[0]=(char)w0.x; q[1]=(char)w0.y; q[2]=(char)w0.z; q[3]=(char)w0.w;
    q[4]=(char)w1.x; q[5]=(char)w1.y; q[6]=(char)w1.z; q[7]=(char)w1.w;
    q[8]=(char)w2.x; q[9]=(char)w2.y; q[10]=(char)w2.z; q[11]=(char)w2.w;
    q[12]=(char)w3.x; q[13]=(char)w3.y; q[14]=(char)w3.z; q[15]=(char)w3.w;
    *(uint4*)(w8 + (size_t)o * IN_F + kb) = *(const uint4*)q;
  }
}

// C[m,o] = sxr[m] * sum_g s_w[g,o] * (int8 dot over group g) + bias[o]
//
// R13: A stays in LDS (verified XOR DMA staging, double-buffered,
// full-tile-ahead -- the latency-tolerant path of the 56us baseline).
// B streams global->VGPR, double-buffered at TILE granularity (bfX/bfY =
// 64 VGPR), prefetched at the START of tile t for tile t+1 -> one full
// tile (~1300+cyc) of latency cover > ~900cyc HBM worst case. This fixes
// R12's failure (half-tile cover on the direct operand, MfmaUtil 16%).
// A B-fragment is 16 contiguous K-bytes per lane: B[bn+wn+j*16+lrow]
// [t*128+(s*4+quad)*16] -- byte-identical to what the old LDS path
// delivered (validated by R12's passing run, mirrored operand).
//
// LDS traffic per block-tile: 96KB -> 48KB (A frag reads 32K + A DMA
// writes 16K), taking LDS (the binding pipe at 56us: 91 B/cyc vs 85
// measured ceiling) off the critical path.
//
// vmcnt FIFO discipline (order pinned by sched_barrier(0)): per tile
//   A-DMA(t+1): 4 loads (oldest) -> B(t+1): 8 loads -> [slices+rescale]
//   -> s_waitcnt vmcnt(8) -> s_barrier
// vmcnt(8) retires exactly the DMA (publishable at the barrier); B stays
// in flight across it. Compiler's wait before next-tile slice-0 MFMA is
// vmcnt(12) (the newer 12), i.e. B gets a full tile to land.
// Registers: accf 64 + bfX/bfY 64 + af 16 + addr ~16 = ~160 VGPR +
// acci 64 AGPR (per-tile scoped, zero-C first MFMA cluster -- the R12
// no-spill pattern, measured 96 VGPR). WRITE_SIZE ~33MB is the sentinel.
__global__ __launch_bounds__(256, 2) void gemm_i8(
    const char* __restrict__ A,     // xq  M x K int8
    const char* __restrict__ B,     // w8  N x K int8
    const float* __restrict__ s_w,  // NG x OUT_F
    const float* __restrict__ sxr,  // M
    const float* __restrict__ bias,
    float* __restrict__ C) {
  __shared__ __attribute__((aligned(16))) char lds[40960];
  unsigned short* sws = (unsigned short*)lds;  // [NG][128] bf16
  const int BUF0 = 8192, BUF1 = 24576;

  const int tid  = threadIdx.x;
  const int wave = tid >> 6;
  const int lane = tid & 63;
  const int bm = blockIdx.y << 7;
  const int bn = blockIdx.x << 7;
  const int wm = (wave >> 1) << 6;
  const int wn = (wave & 1) << 6;
  const int lrow = lane & 15;
  const int quad = lane >> 4;
  const int xlo  = lrow & 7;

  // stage s_w block into LDS as bf16 (K-loop stays free of scalar global)
#pragma unroll
  for (int u = 0; u < 16; ++u) {
    int idx = u * 256 + tid;  // 4096 entries: [g][c]
    int g = idx >> 7, c = idx & 127;
    __hip_bfloat16 h = __float2bfloat16(s_w[(size_t)g * OUT_F + bn + c]);
    sws[idx] = *(unsigned short*)&h;
  }

  // A staging (verified XOR geometry): 1024 16B chunks/tile, chunk
  // c = h*256 + wave*64 + lane: row = h*32 + wave*8 + (lane>>3),
  // kc = (lane&7)^(lane>>3) (h,wave multiples of 8 drop out of row&7).
  // Single base pointer; h-terms compile-time under unroll.
  const char* gA = A + (size_t)(bm + wave * 8 + (lane >> 3)) * IN_F +
                   (((lane & 7) ^ (lane >> 3)) << 4);
  const int lA = wave * 1024;  // + h*4096 (compile-time) within buffer

  // B row base: lane reads rows bn+wn+j*16+lrow, 16B at k = t*128+s*64+quad*16.
  const char* gB = B + (size_t)(bn + wn + lrow) * IN_F + (quad << 4);

  // A fragment LDS addressing: bufA[row*128 + ((slot^xlo)<<4)],
  // row = wm+i*16+lrow, slot = (s<<2)|quad; row&7 == xlo.
  const int aBase = (wm + lrow) * 128;

  f32x4 accf[4][4] = {};
  const v4i zero4 = {0, 0, 0, 0};
  v4i bfX[2][4], bfY[2][4];

  auto rescale = [&](int g, v4i (*acci)[4]) {
    float swv[4];
#pragma unroll
    for (int j = 0; j < 4; ++j) {
      unsigned int u = sws[g * 128 + wn + j * 16 + lrow];
      swv[j] = __uint_as_float(u << 16);
    }
#pragma unroll
    for (int i = 0; i < 4; ++i)
#pragma unroll
      for (int j = 0; j < 4; ++j)
#pragma unroll
        for (int r = 0; r < 4; ++r)
          accf[i][j][r] += swv[j] * (float)acci[i][j][r];
  };

  // TILE(T): A frags from PB (DMA'd last tile), B frags from BC (prefetched
  // last tile); stage A(T+1)->QB (DMA, oldest) then prefetch B(T+1)->BN_;
  // two MFMA slices; rescale; vmcnt(8)+barrier (retires DMA, keeps B flying).
#define TILE(T, PB, QB, BC, BN_, DOSTAGE)                                      \
  {                                                                            \
    const int kt = (T) * GRP;                                                  \
    if (DOSTAGE) {                                                             \
      _Pragma("unroll")                                                        \
      for (int h = 0; h < 4; ++h)                                              \
        async16(gA + (size_t)h * (32 * IN_F) + kt + GRP,                       \
                &lds[QB + lA + h * 4096]);                                     \
      __builtin_amdgcn_sched_barrier(0);                                       \
      _Pragma("unroll")                                                        \
      for (int s = 0; s < 2; ++s)                                              \
        _Pragma("unroll")                                                      \
        for (int j = 0; j < 4; ++j)                                            \
          BN_[s][j] = *(const v4i*)(gB + (size_t)(j * 16) * IN_F + kt + GRP +  \
                                    (s << 6));                                 \
      __builtin_amdgcn_sched_barrier(0);                                       \
    }                                                                          \
    v4i acci[4][4];                                                            \
    {  /* slice 0 (k = kt..kt+64): zero-C MFMAs start the group */             \
      v4i af[4];                                                               \
      _Pragma("unroll")                                                        \
      for (int i = 0; i < 4; ++i)                                              \
        af[i] = *(const v4i*)&lds[PB + aBase + i * 2048 +                      \
                                  ((quad ^ xlo) << 4)];                        \
      __builtin_amdgcn_s_setprio(1);                                           \
      _Pragma("unroll")                                                        \
      for (int i = 0; i < 4; ++i)                                              \
        _Pragma("unroll")                                                      \
        for (int j = 0; j < 4; ++j)                                            \
          acci[i][j] = __builtin_amdgcn_mfma_i32_16x16x64_i8(                  \
              af[i], BC[0][j], zero4, 0, 0, 0);                                \
      __builtin_amdgcn_s_setprio(0);                                           \
    }                                                                          \
    {  /* slice 1 (k = kt+64..kt+128) */                                       \
      v4i af[4];                                                               \
      _Pragma("unroll")                                                        \
      for (int i = 0; i < 4; ++i)                                              \
        af[i] = *(const v4i*)&lds[PB + aBase + i * 2048 +                      \
                                  (((4 | quad) ^ xlo) << 4)];                  \
      __builtin_amdgcn_s_setprio(1);                                           \
      _Pragma("unroll")                                                        \
      for (int i = 0; i < 4; ++i)                                              \
        _Pragma("unroll")                                                      \
        for (int j = 0; j < 4; ++j)                                            \
          acci[i][j] = __builtin_amdgcn_mfma_i32_16x16x64_i8(                  \
              af[i], BC[1][j], acci[i][j], 0, 0, 0);                           \
      __builtin_amdgcn_s_setprio(0);                                           \
    }                                                                          \
    rescale(T, acci);                                                          \
    if (DOSTAGE) {                                                             \
      asm volatile("s_waitcnt vmcnt(8)" ::: "memory");                         \
      __builtin_amdgcn_s_barrier();                                            \
      asm volatile("" ::: "memory");                                           \
    }                                                                          \
  }

  // prologue: A(0) DMA -> BUF0 (oldest), then B(0) -> bfX; vmcnt(8)
  // retires the DMA and keeps B flying; lgkmcnt(0) publishes sws.
#pragma unroll
  for (int h = 0; h < 4; ++h)
    async16(gA + (size_t)h * (32 * IN_F), &lds[BUF0 + lA + h * 4096]);
  __builtin_amdgcn_sched_barrier(0);
#pragma unroll
  for (int s = 0; s < 2; ++s)
#pragma unroll
    for (int j = 0; j < 4; ++j)
      bfX[s][j] = *(const v4i*)(gB + (size_t)(j * 16) * IN_F + (s << 6));
  __builtin_amdgcn_sched_barrier(0);
  asm volatile("s_waitcnt vmcnt(8) lgkmcnt(0)" ::: "memory");
  __builtin_amdgcn_s_barrier();
  asm volatile("" ::: "memory");

  for (int it = 0; it < 16; ++it) {
    TILE(2 * it,     BUF0, BUF1, bfX, bfY, true);
    TILE(2 * it + 1, BUF1, BUF0, bfY, bfX, (it < 15));
  }
#undef TILE

  // Epilogue: C/D layout col=lane&15, row=quad*4+reg (dtype-independent).
#pragma unroll
  for (int i = 0; i < 4; ++i) {
    int r0 = bm + wm + i * 16 + quad * 4;
    float sxv[4];
#pragma unroll
    for (int r = 0; r < 4; ++r) sxv[r] = sxr[r0 + r];
#pragma unroll
    for (int j = 0; j < 4; ++j) {
      int col = bn + wn + j * 16 + lrow;
      float bv = bias[col];
#pragma unroll
      for (int r = 0; r < 4; ++r)
        C[(size_t)(r0 + r) * OUT_F + col] = sxv[r] * accf[i][j][r] + bv;
    }
  }
}

// Correct-but-slow fp32 fallback if workspace is too small.
__global__ void naive_fallback(const float* __restrict__ x, const int* __restrict__ w_q,
                               const float* __restrict__ s_w, const void* __restrict__ perm_raw,
                               const float* __restrict__ bias, float* __restrict__ out) {
  int t = blockIdx.x * blockDim.x + threadIdx.x;
  int m = t >> 12;
  int o = t & 4095;
  const int f = g_perm_is64;
  const long long* p64 = (const long long*)perm_raw;
  const int*       p32 = (const int*)perm_raw;
  const float* xr = x + (size_t)m * IN_F;
  const int*   wr = w_q + (size_t)o * IN_F;
  float acc = 0.f;
  for (int g = 0; g < NG; ++g) {
    float part = 0.f;
    for (int k = 0; k < GRP; ++k) {
      int j = g * GRP + k;
      int pj = f ? (int)p64[j] : p32[j];
      part += xr[pj] * (float)wr[j];
    }
    acc += part * s_w[(size_t)g * OUT_F + o];
  }
  out[t] = acc + bias[o];
}

extern "C" void kernel_launch(void* const* d_in, const int* in_sizes, int n_in,
                              void* d_out, int out_size, void* d_ws, size_t ws_size,
                              hipStream_t stream) {
  const float* x    = (const float*)d_in[0];
  const int*   w_q  = (const int*)d_in[1];
  const float* s_w  = (const float*)d_in[2];
  const void*  perm = d_in[3];   // int64 or int32 -- detected on device
  const float* bias = (const float*)d_in[4];
  float* out = (float*)d_out;

  const size_t xq_bytes = (size_t)M_ROWS * IN_F;            // 8 MiB int8
  const size_t w8_bytes = (size_t)OUT_F * IN_F;             // 16 MiB int8
  const size_t sx_bytes = (size_t)M_ROWS * sizeof(float);   // 8 KiB
  const size_t need = xq_bytes + w8_bytes + sx_bytes;

  if (ws_size < need) {
    decode_flag<<<1, 64, 0, stream>>>(perm);
    naive_fallback<<<(M_ROWS * OUT_F) / 256, 256, 0, stream>>>(x, w_q, s_w, perm, bias, out);
    return;
  }

  char*  xq  = (char*)d_ws;
  char*  w8  = (char*)d_ws + xq_bytes;
  float* sxr = (float*)((char*)d_ws + xq_bytes + w8_bytes);

  prep<<<M_ROWS + OUT_F, 256, 0, stream>>>(x, w_q, perm, xq, w8, sxr);

  dim3 grid(OUT_F / 128, M_ROWS / 128);  // 32 x 16 = 512 blocks, 2/CU
  gemm_i8<<<grid, 256, 0, stream>>>(xq, w8, s_w, sxr, bias, out);
}

// Round 6
// 253.416 us; speedup vs baseline: 1.1858x; 1.1858x over previous
//
#include <hip/hip_runtime.h>
#include <hip/hip_bf16.h>
#include <stdint.h>

#define IN_F   4096
#define OUT_F  4096
#define M_ROWS 2048
#define NG     32
#define GRP    128

typedef int   v4i  __attribute__((ext_vector_type(4)));
typedef float f32x4 __attribute__((ext_vector_type(4)));

typedef const void __attribute__((address_space(1))) cv_g;
typedef void       __attribute__((address_space(3))) v_l;

__device__ __forceinline__ void async16(const void* g, void* l) {
  // global -> LDS DMA, 16B/lane; LDS dest = wave-uniform base + lane*16.
  __builtin_amdgcn_global_load_lds((cv_g*)g, (v_l*)l, 16, 0, 0);
}

// perm dtype flag (fallback path only): 1 if int64, 0 if int32.
__device__ int g_perm_is64;

__global__ void decode_flag(const void* __restrict__ perm_raw) {
  if (threadIdx.x == 0 && blockIdx.x == 0) {
    const int* w = (const int*)perm_raw;
    int ok = 1;
    for (int j = 0; j < 32; ++j) {
      int lo = w[2 * j], hi = w[2 * j + 1];
      if (hi != 0 || lo < 0 || lo >= IN_F) { ok = 0; break; }
    }
    g_perm_is64 = ok;
  }
}

// Fused preprocessing (int8 edition) -- unchanged from verified version.
__global__ __launch_bounds__(256) void prep(const float* __restrict__ x,
                                            const int* __restrict__ w_q,
                                            const void* __restrict__ perm_raw,
                                            char* __restrict__ xq,
                                            char* __restrict__ w8,
                                            float* __restrict__ sxr) {
  __shared__ float sx[IN_F];
  __shared__ float red[4];
  __shared__ int sflag;
  const int b = blockIdx.x;
  const int t = threadIdx.x;

  if (b < M_ROWS) {
    const int m = b;
    const float* xr = x + (size_t)m * IN_F;
#pragma unroll
    for (int u = 0; u < 4; ++u) {
      int idx = (u * 256 + t) * 4;
      *(float4*)&sx[idx] = *(const float4*)&xr[idx];
    }
    if (t < 64) {
      const int* w = (const int*)perm_raw;
      int j = t & 31;
      int lo = w[2 * j], hi = w[2 * j + 1];
      int cond = (hi == 0 && lo >= 0 && lo < IN_F);
      unsigned long long bal = __ballot(cond);
      if (t == 0) sflag = (bal == ~0ull) ? 1 : 0;
    }
    __syncthreads();
    const int f = sflag;
    const long long* p64 = (const long long*)perm_raw;
    const int*       p32 = (const int*)perm_raw;
    const int jb = t * 16;
    float vals[16];
    float lmax = 0.f;
#pragma unroll
    for (int u = 0; u < 16; ++u) {
      int pj = f ? (int)p64[jb + u] : p32[jb + u];
      float v = sx[pj];
      vals[u] = v;
      lmax = fmaxf(lmax, fabsf(v));
    }
#pragma unroll
    for (int d = 1; d < 64; d <<= 1)
      lmax = fmaxf(lmax, __shfl_xor(lmax, d, 64));
    if ((t & 63) == 0) red[t >> 6] = lmax;
    __syncthreads();
    float rmax = fmaxf(fmaxf(red[0], red[1]), fmaxf(red[2], red[3]));
    float inv = (rmax > 0.f) ? 127.f / rmax : 0.f;
    if (t == 0) sxr[m] = rmax / 127.f;
    char q[16] __attribute__((aligned(16)));
#pragma unroll
    for (int u = 0; u < 16; ++u)
      q[u] = (char)__float2int_rn(vals[u] * inv);
    *(uint4*)(xq + (size_t)m * IN_F + jb) = *(const uint4*)q;
  } else {
    const int o  = b - M_ROWS;
    const int kb = t * 16;
    const int* wr = w_q + (size_t)o * IN_F + kb;
    int4 w0 = *(const int4*)(wr + 0);
    int4 w1 = *(const int4*)(wr + 4);
    int4 w2 = *(const int4*)(wr + 8);
    int4 w3 = *(const int4*)(wr + 12);
    char q[16] __attribute__((aligned(16)));
    q[0]=(char)w0.x; q[1]=(char)w0.y; q[2]=(char)w0.z; q[3]=(char)w0.w;
    q[4]=(char)w1.x; q[5]=(char)w1.y; q[6]=(char)w1.z; q[7]=(char)w1.w;
    q[8]=(char)w2.x; q[9]=(char)w2.y; q[10]=(char)w2.z; q[11]=(char)w2.w;
    q[12]=(char)w3.x; q[13]=(char)w3.y; q[14]=(char)w3.z; q[15]=(char)w3.w;
    *(uint4*)(w8 + (size_t)o * IN_F + kb) = *(const uint4*)q;
  }
}

// C[m,o] = sxr[m] * sum_g s_w[g,o] * (int8 dot over group g) + bias[o]
//
// R14 = R13's structure (A in LDS via verified XOR DMA, B direct
// global->VGPR double-buffered at TILE granularity = full-tile latency
// cover; R13 PASSED correctness), spill-proofed:
//  - NO lambdas / array-pointer params. R13's rescale(T, acci) passed the
//    accumulator as a pointer -> compiler demoted acci to scratch
//    (WRITE_SIZE 33->261MB, the real cause of R10/R13 failures; R12 was
//    hand-inlined and did NOT spill at 96 VGPR). Everything here is
//    macro-inlined with compile-time indices.
//  - rescale fused PER OUTPUT ROW: after row i's 8 MFMAs, immediately
//    rescale acci_row (16 regs live instead of 64); row i's rescale VALU
//    fills the MFMA shadow of row i+1 (separate pipes).
//  - __launch_bounds__(256,1): hipcc's allocator under (256,2) targets
//    128 VGPR and spills rather than use the 256/wave available at
//    2 waves/SIMD. (256,1) lifts the cap; occupancy is still 2 blocks/CU
//    (grid 512/256CU, LDS 40KB -> 4 fit, VGPR ~180 -> 8 waves/CU).
// vmcnt FIFO per tile (order pinned by sched_barrier(0)):
//   A-DMA(t+1) x4 (oldest) -> B(t+1) x8 -> [compute] -> vmcnt(8) -> barrier
// vmcnt(8) retires exactly the DMA; B stays in flight across the barrier
// with a full tile (~1300cy) to land before its compiler-inserted wait.
// Register tally (static): accf 64 + bfX/bfY 64 + acci 16 + af 8 + swv 4
// + addressing ~20 ~= 180 < 256. Sentinels: WRITE_SIZE ~33MB, VGPR<=208.
__global__ __launch_bounds__(256, 1) void gemm_i8(
    const char* __restrict__ A,     // xq  M x K int8
    const char* __restrict__ B,     // w8  N x K int8
    const float* __restrict__ s_w,  // NG x OUT_F
    const float* __restrict__ sxr,  // M
    const float* __restrict__ bias,
    float* __restrict__ C) {
  __shared__ __attribute__((aligned(16))) char lds[40960];
  unsigned short* sws = (unsigned short*)lds;  // [NG][128] bf16
  const int BUF0 = 8192, BUF1 = 24576;

  const int tid  = threadIdx.x;
  const int wave = tid >> 6;
  const int lane = tid & 63;
  const int bm = blockIdx.y << 7;
  const int bn = blockIdx.x << 7;
  const int wm = (wave >> 1) << 6;
  const int wn = (wave & 1) << 6;
  const int lrow = lane & 15;
  const int quad = lane >> 4;
  const int xlo  = lrow & 7;

  // stage s_w block into LDS as bf16 (K-loop stays free of scalar global)
#pragma unroll
  for (int u = 0; u < 16; ++u) {
    int idx = u * 256 + tid;  // 4096 entries: [g][c]
    int g = idx >> 7, c = idx & 127;
    __hip_bfloat16 h = __float2bfloat16(s_w[(size_t)g * OUT_F + bn + c]);
    sws[idx] = *(unsigned short*)&h;
  }

  // A staging (verified XOR geometry): 1024 16B chunks/tile, chunk
  // c = h*256 + wave*64 + lane: row = h*32 + wave*8 + (lane>>3),
  // kc = (lane&7)^(lane>>3). Single base pointer; h-terms compile-time.
  const char* gA = A + (size_t)(bm + wave * 8 + (lane >> 3)) * IN_F +
                   (((lane & 7) ^ (lane >> 3)) << 4);
  const int lA = wave * 1024;  // + h*4096 (compile-time) within buffer

  // B row base: lane reads rows bn+wn+j*16+lrow, 16B at k = t*128+s*64+quad*16.
  const char* gB = B + (size_t)(bn + wn + lrow) * IN_F + (quad << 4);

  // A fragment LDS addressing: buf[aBase + i*2048 + ((slot^xlo)<<4)],
  // slot = s*4+quad (row&7 == xlo for all fragment rows).
  const int aBase = (wm + lrow) * 128;

  f32x4 accf[4][4] = {};
  const v4i zero4 = {0, 0, 0, 0};
  v4i bfX[2][4], bfY[2][4];

  // TILE: A frags from PB (DMA'd last tile), B frags from BC (prefetched
  // last tile); stage A(T+1)->QB (oldest) then prefetch B(T+1)->BN_;
  // per-row {2 ds_reads, 8 MFMAs, rescale}; vmcnt(8)+barrier.
#define TILE(T, PB, QB, BC, BN_, DOSTAGE)                                      \
  {                                                                            \
    const int kt = (T) * GRP;                                                  \
    if (DOSTAGE) {                                                             \
      _Pragma("unroll")                                                        \
      for (int h = 0; h < 4; ++h)                                              \
        async16(gA + (size_t)h * (32 * IN_F) + kt + GRP,                       \
                &lds[QB + lA + h * 4096]);                                     \
      __builtin_amdgcn_sched_barrier(0);                                       \
      _Pragma("unroll")                                                        \
      for (int s = 0; s < 2; ++s)                                              \
        _Pragma("unroll")                                                      \
        for (int j = 0; j < 4; ++j)                                            \
          BN_[s][j] = *(const v4i*)(gB + (size_t)(j * 16) * IN_F + kt + GRP +  \
                                    (s << 6));                                 \
      __builtin_amdgcn_sched_barrier(0);                                       \
    }                                                                          \
    float swv[4];                                                              \
    _Pragma("unroll")                                                          \
    for (int j = 0; j < 4; ++j) {                                              \
      unsigned int u = sws[(T) * 128 + wn + j * 16 + lrow];                    \
      swv[j] = __uint_as_float(u << 16);                                       \
    }                                                                          \
    _Pragma("unroll")                                                          \
    for (int i = 0; i < 4; ++i) {                                              \
      v4i af0 = *(const v4i*)&lds[PB + aBase + i * 2048 +                      \
                                  ((quad ^ xlo) << 4)];                        \
      v4i af1 = *(const v4i*)&lds[PB + aBase + i * 2048 +                      \
                                  (((4 | quad) ^ xlo) << 4)];                  \
      v4i ac0, ac1, ac2, ac3;                                                  \
      __builtin_amdgcn_s_setprio(1);                                           \
      ac0 = __builtin_amdgcn_mfma_i32_16x16x64_i8(af0, BC[0][0], zero4, 0, 0, 0); \
      ac1 = __builtin_amdgcn_mfma_i32_16x16x64_i8(af0, BC[0][1], zero4, 0, 0, 0); \
      ac2 = __builtin_amdgcn_mfma_i32_16x16x64_i8(af0, BC[0][2], zero4, 0, 0, 0); \
      ac3 = __builtin_amdgcn_mfma_i32_16x16x64_i8(af0, BC[0][3], zero4, 0, 0, 0); \
      ac0 = __builtin_amdgcn_mfma_i32_16x16x64_i8(af1, BC[1][0], ac0, 0, 0, 0);   \
      ac1 = __builtin_amdgcn_mfma_i32_16x16x64_i8(af1, BC[1][1], ac1, 0, 0, 0);   \
      ac2 = __builtin_amdgcn_mfma_i32_16x16x64_i8(af1, BC[1][2], ac2, 0, 0, 0);   \
      ac3 = __builtin_amdgcn_mfma_i32_16x16x64_i8(af1, BC[1][3], ac3, 0, 0, 0);   \
      __builtin_amdgcn_s_setprio(0);                                           \
      _Pragma("unroll")                                                        \
      for (int r = 0; r < 4; ++r) {                                            \
        accf[i][0][r] += swv[0] * (float)ac0[r];                               \
        accf[i][1][r] += swv[1] * (float)ac1[r];                               \
        accf[i][2][r] += swv[2] * (float)ac2[r];                               \
        accf[i][3][r] += swv[3] * (float)ac3[r];                               \
      }                                                                        \
    }                                                                          \
    if (DOSTAGE) {                                                             \
      asm volatile("s_waitcnt vmcnt(8)" ::: "memory");                         \
      __builtin_amdgcn_s_barrier();                                            \
      asm volatile("" ::: "memory");                                           \
    }                                                                          \
  }

  // prologue: A(0) DMA -> BUF0 (oldest), then B(0) -> bfX; vmcnt(8)
  // retires the DMA and keeps B flying; lgkmcnt(0) publishes sws.
#pragma unroll
  for (int h = 0; h < 4; ++h)
    async16(gA + (size_t)h * (32 * IN_F), &lds[BUF0 + lA + h * 4096]);
  __builtin_amdgcn_sched_barrier(0);
#pragma unroll
  for (int s = 0; s < 2; ++s)
#pragma unroll
    for (int j = 0; j < 4; ++j)
      bfX[s][j] = *(const v4i*)(gB + (size_t)(j * 16) * IN_F + (s << 6));
  __builtin_amdgcn_sched_barrier(0);
  asm volatile("s_waitcnt vmcnt(8) lgkmcnt(0)" ::: "memory");
  __builtin_amdgcn_s_barrier();
  asm volatile("" ::: "memory");

  for (int it = 0; it < 16; ++it) {
    TILE(2 * it,     BUF0, BUF1, bfX, bfY, true);
    TILE(2 * it + 1, BUF1, BUF0, bfY, bfX, (it < 15));
  }
#undef TILE

  // Epilogue: C/D layout col=lane&15, row=quad*4+reg (dtype-independent).
#pragma unroll
  for (int i = 0; i < 4; ++i) {
    int r0 = bm + wm + i * 16 + quad * 4;
    float sxv[4];
#pragma unroll
    for (int r = 0; r < 4; ++r) sxv[r] = sxr[r0 + r];
#pragma unroll
    for (int j = 0; j < 4; ++j) {
      int col = bn + wn + j * 16 + lrow;
      float bv = bias[col];
#pragma unroll
      for (int r = 0; r < 4; ++r)
        C[(size_t)(r0 + r) * OUT_F + col] = sxv[r] * accf[i][j][r] + bv;
    }
  }
}

// Correct-but-slow fp32 fallback if workspace is too small.
__global__ void naive_fallback(const float* __restrict__ x, const int* __restrict__ w_q,
                               const float* __restrict__ s_w, const void* __restrict__ perm_raw,
                               const float* __restrict__ bias, float* __restrict__ out) {
  int t = blockIdx.x * blockDim.x + threadIdx.x;
  int m = t >> 12;
  int o = t & 4095;
  const int f = g_perm_is64;
  const long long* p64 = (const long long*)perm_raw;
  const int*       p32 = (const int*)perm_raw;
  const float* xr = x + (size_t)m * IN_F;
  const int*   wr = w_q + (size_t)o * IN_F;
  float acc = 0.f;
  for (int g = 0; g < NG; ++g) {
    float part = 0.f;
    for (int k = 0; k < GRP; ++k) {
      int j = g * GRP + k;
      int pj = f ? (int)p64[j] : p32[j];
      part += xr[pj] * (float)wr[j];
    }
    acc += part * s_w[(size_t)g * OUT_F + o];
  }
  out[t] = acc + bias[o];
}

extern "C" void kernel_launch(void* const* d_in, const int* in_sizes, int n_in,
                              void* d_out, int out_size, void* d_ws, size_t ws_size,
                              hipStream_t stream) {
  const float* x    = (const float*)d_in[0];
  const int*   w_q  = (const int*)d_in[1];
  const float* s_w  = (const float*)d_in[2];
  const void*  perm = d_in[3];   // int64 or int32 -- detected on device
  const float* bias = (const float*)d_in[4];
  float* out = (float*)d_out;

  const size_t xq_bytes = (size_t)M_ROWS * IN_F;            // 8 MiB int8
  const size_t w8_bytes = (size_t)OUT_F * IN_F;             // 16 MiB int8
  const size_t sx_bytes = (size_t)M_ROWS * sizeof(float);   // 8 KiB
  const size_t need = xq_bytes + w8_bytes + sx_bytes;

  if (ws_size < need) {
    decode_flag<<<1, 64, 0, stream>>>(perm);
    naive_fallback<<<(M_ROWS * OUT_F) / 256, 256, 0, stream>>>(x, w_q, s_w, perm, bias, out);
    return;
  }

  char*  xq  = (char*)d_ws;
  char*  w8  = (char*)d_ws + xq_bytes;
  float* sxr = (float*)((char*)d_ws + xq_bytes + w8_bytes);

  prep<<<M_ROWS + OUT_F, 256, 0, stream>>>(x, w_q, perm, xq, w8, sxr);

  dim3 grid(OUT_F / 128, M_ROWS / 128);  // 32 x 16 = 512 blocks, 2/CU
  gemm_i8<<<grid, 256, 0, stream>>>(xq, w8, s_w, sxr, bias, out);
}

// Round 7
// 194.662 us; speedup vs baseline: 1.5437x; 1.3018x over previous
//
#include <hip/hip_runtime.h>
#include <hip/hip_bf16.h>
#include <stdint.h>

#define IN_F   4096
#define OUT_F  4096
#define M_ROWS 2048
#define NG     32
#define GRP    128

typedef int   v4i  __attribute__((ext_vector_type(4)));
typedef float f32x4 __attribute__((ext_vector_type(4)));

typedef const void __attribute__((address_space(1))) cv_g;
typedef void       __attribute__((address_space(3))) v_l;

__device__ __forceinline__ void async16(const void* g, void* l) {
  // global -> LDS DMA, 16B/lane; LDS dest = wave-uniform base + lane*16.
  __builtin_amdgcn_global_load_lds((cv_g*)g, (v_l*)l, 16, 0, 0);
}

// perm dtype flag (fallback path only): 1 if int64, 0 if int32.
__device__ int g_perm_is64;

__global__ void decode_flag(const void* __restrict__ perm_raw) {
  if (threadIdx.x == 0 && blockIdx.x == 0) {
    const int* w = (const int*)perm_raw;
    int ok = 1;
    for (int j = 0; j < 32; ++j) {
      int lo = w[2 * j], hi = w[2 * j + 1];
      if (hi != 0 || lo < 0 || lo >= IN_F) { ok = 0; break; }
    }
    g_perm_is64 = ok;
  }
}

// Fused preprocessing (int8 edition) -- unchanged from verified version.
__global__ __launch_bounds__(256) void prep(const float* __restrict__ x,
                                            const int* __restrict__ w_q,
                                            const void* __restrict__ perm_raw,
                                            char* __restrict__ xq,
                                            char* __restrict__ w8,
                                            float* __restrict__ sxr) {
  __shared__ float sx[IN_F];
  __shared__ float red[4];
  __shared__ int sflag;
  const int b = blockIdx.x;
  const int t = threadIdx.x;

  if (b < M_ROWS) {
    const int m = b;
    const float* xr = x + (size_t)m * IN_F;
#pragma unroll
    for (int u = 0; u < 4; ++u) {
      int idx = (u * 256 + t) * 4;
      *(float4*)&sx[idx] = *(const float4*)&xr[idx];
    }
    if (t < 64) {
      const int* w = (const int*)perm_raw;
      int j = t & 31;
      int lo = w[2 * j], hi = w[2 * j + 1];
      int cond = (hi == 0 && lo >= 0 && lo < IN_F);
      unsigned long long bal = __ballot(cond);
      if (t == 0) sflag = (bal == ~0ull) ? 1 : 0;
    }
    __syncthreads();
    const int f = sflag;
    const long long* p64 = (const long long*)perm_raw;
    const int*       p32 = (const int*)perm_raw;
    const int jb = t * 16;
    float vals[16];
    float lmax = 0.f;
#pragma unroll
    for (int u = 0; u < 16; ++u) {
      int pj = f ? (int)p64[jb + u] : p32[jb + u];
      float v = sx[pj];
      vals[u] = v;
      lmax = fmaxf(lmax, fabsf(v));
    }
#pragma unroll
    for (int d = 1; d < 64; d <<= 1)
      lmax = fmaxf(lmax, __shfl_xor(lmax, d, 64));
    if ((t & 63) == 0) red[t >> 6] = lmax;
    __syncthreads();
    float rmax = fmaxf(fmaxf(red[0], red[1]), fmaxf(red[2], red[3]));
    float inv = (rmax > 0.f) ? 127.f / rmax : 0.f;
    if (t == 0) sxr[m] = rmax / 127.f;
    char q[16] __attribute__((aligned(16)));
#pragma unroll
    for (int u = 0; u < 16; ++u)
      q[u] = (char)__float2int_rn(vals[u] * inv);
    *(uint4*)(xq + (size_t)m * IN_F + jb) = *(const uint4*)q;
  } else {
    const int o  = b - M_ROWS;
    const int kb = t * 16;
    const int* wr = w_q + (size_t)o * IN_F + kb;
    int4 w0 = *(const int4*)(wr + 0);
    int4 w1 = *(const int4*)(wr + 4);
    int4 w2 = *(const int4*)(wr + 8);
    int4 w3 = *(const int4*)(wr + 12);
    char q[16] __attribute__((aligned(16)));
    q[0]=(char)w0.x; q[1]=(char)w0.y; q[2]=(char)w0.z; q[3]=(char)w0.w;
    q[4]=(char)w1.x; q[5]=(char)w1.y; q[6]=(char)w1.z; q[7]=(char)w1.w;
    q[8]=(char)w2.x; q[9]=(char)w2.y; q[10]=(char)w2.z; q[11]=(char)w2.w;
    q[12]=(char)w3.x; q[13]=(char)w3.y; q[14]=(char)w3.z; q[15]=(char)w3.w;
    *(uint4*)(w8 + (size_t)o * IN_F + kb) = *(const uint4*)q;
  }
}

// C[m,o] = sxr[m] * sum_g s_w[g,o] * (int8 dot over group g) + bias[o]
//
// R15 = the EXACT verified R0 kernel (int8 MFMA, 128x128 tile, BK=128
// double-buffered, 2 blocks/CU, 120 VGPR no-spill, gemm 56.5us) with ONE
// change: counted-vmcnt barriers (T4), the only catalog technique never
// tested in isolation on this geometry (R9 bundled it with a 1-block/CU
// geometry change that destroyed cross-block overlap -> null).
//
// R0's __syncthreads() lowered to s_waitcnt vmcnt(0): a FULL DMA-queue
// drain per tile, stalling on the last-issued load (zero latency cover).
// Here each tile-end sync splits into:
//   [compute reads done]  lgkmcnt(0); s_barrier          (WAR: buf free)
//   stage next tile (8 DMAs into that buf)
//   s_waitcnt vmcnt(8)                                   (counted)
//   s_barrier                                            (publish other buf)
// FIFO per thread: outstanding = 8 old (a full compute phase to land)
// + 8 new -> vmcnt(8) retires exactly the old 8; the new 8 cross the
// barrier in flight. Only the final tile uses vmcnt(0). Direct-register
// operand streaming is falsified (R12: 83us, R14: 115us) -- the DMA+LDS
// pipeline with counted waits is the remaining lever on this structure.
__global__ __launch_bounds__(256, 2) void gemm_i8(
    const char* __restrict__ A,     // xq  M x K int8
    const char* __restrict__ B,     // w8  N x K int8
    const float* __restrict__ s_w,  // NG x OUT_F
    const float* __restrict__ sxr,  // M
    const float* __restrict__ bias,
    float* __restrict__ C) {
  __shared__ char smem[2][32768];           // per buf: A 16384 | B 16384 bytes
  __shared__ unsigned short sws[NG * 128];  // s_w for this block's 128 cols, bf16

  const int tid  = threadIdx.x;
  const int wave = tid >> 6;
  const int lane = tid & 63;
  const int bm = blockIdx.y << 7;
  const int bn = blockIdx.x << 7;
  const int wm = (wave >> 1) << 6;
  const int wn = (wave & 1) << 6;
  const int lrow = lane & 15;
  const int quad = lane >> 4;

  // stage s_w block into LDS as bf16 (keeps the K-loop free of global loads)
#pragma unroll
  for (int u = 0; u < 16; ++u) {
    int idx = u * 256 + tid;               // [g][c], c = local col
    int g = idx >> 7, c = idx & 127;
    __hip_bfloat16 h = __float2bfloat16(s_w[(size_t)g * OUT_F + bn + c]);
    sws[idx] = *(unsigned short*)&h;
  }

  f32x4 accf[4][4] = {};

  // Staging: per buf 2048 chunks of 16B. Round r = h*4+wave (h=0..7) covers
  // chunks c = r*64 + lane. c<1024 -> A (row=c>>3), else B. kc = (c&7)^(row&7).
  const char* gp[8];
  int lofs[8];
#pragma unroll
  for (int h = 0; h < 8; ++h) {
    int c0 = (h * 4 + wave) * 64;
    int c  = c0 + lane;
    if (c < 1024) {
      int row = c >> 3;
      int kc  = (c & 7) ^ (row & 7);
      gp[h]   = A + (size_t)(bm + row) * IN_F + kc * 16;
      lofs[h] = c0 * 16;
    } else {
      int cb  = c - 1024;
      int row = cb >> 3;
      int kc  = (cb & 7) ^ (row & 7);
      gp[h]   = B + (size_t)(bn + row) * IN_F + kc * 16;
      lofs[h] = 16384 + (c0 - 1024) * 16;
    }
  }

  auto stage = [&](int p, int kn) {
#pragma unroll
    for (int h = 0; h < 8; ++h)
      async16(gp[h] + kn, &smem[p][lofs[h]]);
  };

  auto compute = [&](int p, int g) {
    const char* bufA = smem[p];
    const char* bufB = smem[p] + 16384;
    v4i acci[4][4] = {};
#pragma unroll
    for (int s = 0; s < 2; ++s) {
      v4i af[4], bf[4];
#pragma unroll
      for (int i = 0; i < 4; ++i) {
        int row = wm + i * 16 + lrow;
        af[i] = *(const v4i*)&bufA[row * 128 + (((s << 2) + quad) ^ (row & 7)) * 16];
      }
#pragma unroll
      for (int j = 0; j < 4; ++j) {
        int row = wn + j * 16 + lrow;
        bf[j] = *(const v4i*)&bufB[row * 128 + (((s << 2) + quad) ^ (row & 7)) * 16];
      }
#pragma unroll
      for (int i = 0; i < 4; ++i)
#pragma unroll
        for (int j = 0; j < 4; ++j)
          acci[i][j] = __builtin_amdgcn_mfma_i32_16x16x64_i8(af[i], bf[j], acci[i][j], 0, 0, 0);
    }
    // per-group rescale (exact int32 -> f32, scaled by s_w[g, col])
    float swv[4];
#pragma unroll
    for (int j = 0; j < 4; ++j) {
      unsigned int u = sws[g * 128 + wn + j * 16 + lrow];
      swv[j] = __uint_as_float(u << 16);
    }
#pragma unroll
    for (int i = 0; i < 4; ++i)
#pragma unroll
      for (int j = 0; j < 4; ++j)
#pragma unroll
        for (int r = 0; r < 4; ++r)
          accf[i][j][r] += swv[j] * (float)acci[i][j][r];
  };

  // prologue: stage tiles 0 and 1 (8 DMAs each; queue = 16). vmcnt(8)
  // retires exactly tile 0's DMAs; tile 1's stay in flight across the
  // barrier with a full compute phase to land. lgkmcnt(0) publishes sws.
  stage(0, 0);
  stage(1, 128);
  asm volatile("s_waitcnt vmcnt(8) lgkmcnt(0)" ::: "memory");
  __builtin_amdgcn_s_barrier();
  asm volatile("" ::: "memory");

  for (int k0 = 0; k0 < IN_F; k0 += 256) {
    compute(0, k0 >> 7);                       // read buf0 (tile e)
    asm volatile("s_waitcnt lgkmcnt(0)" ::: "memory");
    __builtin_amdgcn_s_barrier();              // WAR: all waves done with buf0
    asm volatile("" ::: "memory");
    if (k0 + 256 < IN_F) {
      stage(0, k0 + 256);                      // tile e+2 -> buf0
      asm volatile("s_waitcnt vmcnt(8)" ::: "memory");  // retire tile e+1 DMAs
    } else {
      asm volatile("s_waitcnt vmcnt(0)" ::: "memory");  // tail: drain tile 31
    }
    __builtin_amdgcn_s_barrier();              // publish buf1
    asm volatile("" ::: "memory");
    compute(1, (k0 >> 7) + 1);                 // read buf1 (tile e+1)
    if (k0 + 256 < IN_F) {
      asm volatile("s_waitcnt lgkmcnt(0)" ::: "memory");
      __builtin_amdgcn_s_barrier();            // WAR: all waves done with buf1
      asm volatile("" ::: "memory");
      stage(1, k0 + 384);                      // tile e+3 -> buf1
      asm volatile("s_waitcnt vmcnt(8)" ::: "memory");  // retire tile e+2 DMAs
      __builtin_amdgcn_s_barrier();            // publish buf0
      asm volatile("" ::: "memory");
    }
  }

  // Epilogue: C/D layout col=lane&15, row=quad*4+reg (dtype-independent,
  // m89/m121-128). Apply per-row x-scale + bias.
#pragma unroll
  for (int i = 0; i < 4; ++i) {
    int r0 = bm + wm + i * 16 + quad * 4;
    float sxv[4];
#pragma unroll
    for (int r = 0; r < 4; ++r) sxv[r] = sxr[r0 + r];  // quad-broadcast loads
#pragma unroll
    for (int j = 0; j < 4; ++j) {
      int col = bn + wn + j * 16 + lrow;
      float bv = bias[col];
#pragma unroll
      for (int r = 0; r < 4; ++r)
        C[(size_t)(r0 + r) * OUT_F + col] = sxv[r] * accf[i][j][r] + bv;
    }
  }
}

// Correct-but-slow fp32 fallback if workspace is too small.
__global__ void naive_fallback(const float* __restrict__ x, const int* __restrict__ w_q,
                               const float* __restrict__ s_w, const void* __restrict__ perm_raw,
                               const float* __restrict__ bias, float* __restrict__ out) {
  int t = blockIdx.x * blockDim.x + threadIdx.x;
  int m = t >> 12;
  int o = t & 4095;
  const int f = g_perm_is64;
  const long long* p64 = (const long long*)perm_raw;
  const int*       p32 = (const int*)perm_raw;
  const float* xr = x + (size_t)m * IN_F;
  const int*   wr = w_q + (size_t)o * IN_F;
  float acc = 0.f;
  for (int g = 0; g < NG; ++g) {
    float part = 0.f;
    for (int k = 0; k < GRP; ++k) {
      int j = g * GRP + k;
      int pj = f ? (int)p64[j] : p32[j];
      part += xr[pj] * (float)wr[j];
    }
    acc += part * s_w[(size_t)g * OUT_F + o];
  }
  out[t] = acc + bias[o];
}

extern "C" void kernel_launch(void* const* d_in, const int* in_sizes, int n_in,
                              void* d_out, int out_size, void* d_ws, size_t ws_size,
                              hipStream_t stream) {
  const float* x    = (const float*)d_in[0];
  const int*   w_q  = (const int*)d_in[1];
  const float* s_w  = (const float*)d_in[2];
  const void*  perm = d_in[3];   // int64 or int32 -- detected on device
  const float* bias = (const float*)d_in[4];
  float* out = (float*)d_out;

  const size_t xq_bytes = (size_t)M_ROWS * IN_F;            // 8 MiB int8
  const size_t w8_bytes = (size_t)OUT_F * IN_F;             // 16 MiB int8
  const size_t sx_bytes = (size_t)M_ROWS * sizeof(float);   // 8 KiB
  const size_t need = xq_bytes + w8_bytes + sx_bytes;

  if (ws_size < need) {
    decode_flag<<<1, 64, 0, stream>>>(perm);
    naive_fallback<<<(M_ROWS * OUT_F) / 256, 256, 0, stream>>>(x, w_q, s_w, perm, bias, out);
    return;
  }

  char*  xq  = (char*)d_ws;
  char*  w8  = (char*)d_ws + xq_bytes;
  float* sxr = (float*)((char*)d_ws + xq_bytes + w8_bytes);

  prep<<<M_ROWS + OUT_F, 256, 0, stream>>>(x, w_q, perm, xq, w8, sxr);

  dim3 grid(OUT_F / 128, M_ROWS / 128);  // 32 x 16 = 512 blocks, 2/CU
  gemm_i8<<<grid, 256, 0, stream>>>(xq, w8, s_w, sxr, bias, out);
}